// Round 2
// 265.898 us; speedup vs baseline: 1.0214x; 1.0214x over previous
//
#include <hip/hip_runtime.h>
#include <math.h>

// Problem constants (fixed by the reference)
#define Bn   32
#define Cn   256
#define Kn   3
#define HWn  4096      // 64*64
#define HW4n 1024      // HW in float4 units
#define BN_EPS 1e-5f
#define SPC  16        // channels per strip (stencil)
#define NSTRIP (Cn / SPC)

typedef float f4 __attribute__((ext_vector_type(4)));

// ---------------------------------------------------------------------------
// Kernel 1: global average pool. One block per (b,c); 256 threads each read
// 4 float4 (16 floats) -> block reduce -> gap[b*C+c].
// Normal (caching) loads on purpose: this pass warms x into Infinity Cache
// (x = 128 MiB, L3 = 256 MiB -> fully resident) for the stencil pass.
// ---------------------------------------------------------------------------
__global__ __launch_bounds__(256) void gap_kernel(const float* __restrict__ x,
                                                  float* __restrict__ gap) {
    const int bc = blockIdx.x;                     // b*Cn + c
    const f4* px = (const f4*)(x + (size_t)bc * HWn);
    const int t = threadIdx.x;
    float s = 0.f;
#pragma unroll
    for (int i = 0; i < 4; ++i) {
        f4 v = px[t + i * 256];
        s += (v.x + v.y) + (v.z + v.w);
    }
    // wave64 shuffle reduce
#pragma unroll
    for (int off = 32; off > 0; off >>= 1) s += __shfl_down(s, off, 64);
    __shared__ float ls[4];
    const int wave = t >> 6, lane = t & 63;
    if (lane == 0) ls[wave] = s;
    __syncthreads();
    if (t == 0) {
        gap[bc] = (ls[0] + ls[1] + ls[2] + ls[3]) * (1.0f / (float)HWn);
    }
}

// ---------------------------------------------------------------------------
// Kernel 2 (fused filt + stencil):
//  - issue the first two stencil x-loads (xm, xc) immediately -> in flight
//  - compute this block's 48 filter coefficients from gap (LDS) x conv_w
//    (L2-resident, 768 KiB): 48 dots of length 256, 4 threads per dot;
//    fold BN(eval)+sigmoid+gamma/beta into a0/a1/a2 stencil coefficients
//  - 3-tap channel stencil, rolling register window over SPC=16 channels.
// x reads: NORMAL loads (x is L3-resident after gap pass).
// out writes: NON-TEMPORAL (write-once; must not evict x from L3 mid-pass).
// Reflect edges: c==0 uses x[1]; c==C-1 uses x[C-2].
// 2048 blocks -> 8 blocks/CU -> 32 waves/CU (max occupancy).
// ---------------------------------------------------------------------------
__global__ __launch_bounds__(256) void stencil_kernel(
        const float* __restrict__ x, const float* __restrict__ gap,
        const float* __restrict__ conv_w,
        const float* __restrict__ bn_w, const float* __restrict__ bn_b,
        const float* __restrict__ bn_mean, const float* __restrict__ bn_var,
        const float* __restrict__ gamma, const float* __restrict__ beta,
        float* __restrict__ out) {
    const int gid   = blockIdx.x * 256 + threadIdx.x;
    const int hw4   = gid & (HW4n - 1);
    const int strip = (gid >> 10) & (NSTRIP - 1);
    const int b     = gid >> 14;
    const int c0    = strip * SPC;
    const int t     = threadIdx.x;

    // ---- issue first stencil loads early; they stay in flight while the
    // ---- filter coefficients are computed below
    const f4* px = (const f4*)x;
    const size_t base = (size_t)b * Cn * HW4n + hw4;   // float4 units
    const int cm = (c0 == 0) ? 1 : c0 - 1;             // reflect at c=0
    f4 xm = px[base + (size_t)cm * HW4n];
    f4 xc = px[base + (size_t)c0 * HW4n];

    // ---- filter phase: 48 outputs (k=0..2, cc=0..15), 4-way split-K ----
    __shared__ __align__(16) float gap_s[Cn];
    __shared__ float a0s[SPC], a1s[SPC], a2s[SPC];
    gap_s[t] = gap[b * Cn + t];
    __syncthreads();
    if (t < 192) {
        const int ol = t >> 2, p = t & 3;              // ol = k*16+cc
        const int k = ol >> 4, cc = ol & 15;
        const int c = c0 + cc;
        const int o = k * Cn + c;
        const f4* w4 = (const f4*)(conv_w + (size_t)o * Cn) + p * 16;
        const f4* g4 = ((const f4*)gap_s) + p * 16;
        float acc = 0.f;
#pragma unroll
        for (int i = 0; i < 16; ++i) {
            f4 g = g4[i], w = w4[i];
            acc += g.x * w.x + g.y * w.y + g.z * w.z + g.w * w.w;
        }
        acc += __shfl_down(acc, 2, 4);
        acc += __shfl_down(acc, 1, 4);
        if (p == 0) {
            float fv = (acc - bn_mean[o]) * rsqrtf(bn_var[o] + BN_EPS) * bn_w[o] + bn_b[o];
            float sg = 1.0f / (1.0f + expf(-fv));
            float a  = (k == 1) ? (sg * gamma[c] + beta[c]) : (sg * gamma[c]);
            if (k == 0) a0s[cc] = a; else if (k == 1) a1s[cc] = a; else a2s[cc] = a;
        }
    }
    __syncthreads();

    // ---- stencil phase: rolling register window over 16 channels --------
    f4* pout = (f4*)out;
#pragma unroll 4
    for (int i = 0; i < SPC; ++i) {
        const int c   = c0 + i;
        const int cnn = (c == Cn - 1) ? (Cn - 2) : (c + 1);  // reflect at c=C-1
        f4 xn = px[base + (size_t)cnn * HW4n];
        const float a0 = a0s[i], a1 = a1s[i], a2 = a2s[i];
        f4 o;
        o.x = fmaf(a0, xm.x, fmaf(a1, xc.x, a2 * xn.x));
        o.y = fmaf(a0, xm.y, fmaf(a1, xc.y, a2 * xn.y));
        o.z = fmaf(a0, xm.z, fmaf(a1, xc.z, a2 * xn.z));
        o.w = fmaf(a0, xm.w, fmaf(a1, xc.w, a2 * xn.w));
        __builtin_nontemporal_store(o, &pout[base + (size_t)c * HW4n]);
        xm = xc;
        xc = xn;
    }
}

extern "C" void kernel_launch(void* const* d_in, const int* in_sizes, int n_in,
                              void* d_out, int out_size, void* d_ws, size_t ws_size,
                              hipStream_t stream) {
    const float* x       = (const float*)d_in[0];
    const float* conv_w  = (const float*)d_in[1];
    const float* bn_w    = (const float*)d_in[2];
    const float* bn_b    = (const float*)d_in[3];
    const float* bn_mean = (const float*)d_in[4];
    const float* bn_var  = (const float*)d_in[5];
    const float* gamma   = (const float*)d_in[6];
    const float* beta    = (const float*)d_in[7];
    float* out = (float*)d_out;

    float* gap = (float*)d_ws;            // [B*C] = 32 KiB

    gap_kernel<<<Bn * Cn, 256, 0, stream>>>(x, gap);
    stencil_kernel<<<(Bn * NSTRIP * HW4n) / 256, 256, 0, stream>>>(
        x, gap, conv_w, bn_w, bn_b, bn_mean, bn_var, gamma, beta, out);
}

// Round 3
// 263.954 us; speedup vs baseline: 1.0289x; 1.0074x over previous
//
#include <hip/hip_runtime.h>
#include <math.h>

// Problem constants (fixed by the reference)
#define Bn   32
#define Cn   256
#define Kn   3
#define HWn  4096      // 64*64
#define HW4n 1024      // HW in float4 units
#define BN_EPS 1e-5f
#define SPC  16        // channels per strip (stencil)
#define NSTRIP (Cn / SPC)

typedef float f4 __attribute__((ext_vector_type(4)));

// ---------------------------------------------------------------------------
// Kernel 1: global average pool. One block per (b,c); 256 threads each read
// 4 float4 (16 floats) -> block reduce -> gap[b*C+c].
// Normal (caching) loads on purpose: this pass warms x into Infinity Cache
// (x = 128 MiB, L3 = 256 MiB -> fully resident) for the stencil pass.
// ---------------------------------------------------------------------------
__global__ __launch_bounds__(256) void gap_kernel(const float* __restrict__ x,
                                                  float* __restrict__ gap) {
    const int bc = blockIdx.x;                     // b*Cn + c
    const f4* px = (const f4*)(x + (size_t)bc * HWn);
    const int t = threadIdx.x;
    float s = 0.f;
#pragma unroll
    for (int i = 0; i < 4; ++i) {
        f4 v = px[t + i * 256];
        s += (v.x + v.y) + (v.z + v.w);
    }
    // wave64 shuffle reduce
#pragma unroll
    for (int off = 32; off > 0; off >>= 1) s += __shfl_down(s, off, 64);
    __shared__ float ls[4];
    const int wave = t >> 6, lane = t & 63;
    if (lane == 0) ls[wave] = s;
    __syncthreads();
    if (t == 0) {
        gap[bc] = (ls[0] + ls[1] + ls[2] + ls[3]) * (1.0f / (float)HWn);
    }
}

// ---------------------------------------------------------------------------
// Kernel 2 (fused filt + stencil), 2 float4 pixels per thread for 2x MLP:
//  - issue the first four stencil x-loads (xm/xc for both pixels) early;
//    they stay in flight across the filter phase
//  - compute this block's 48 filter coefficients from gap (LDS) x conv_w
//    (L2-resident): 48 dots of length 256, 4 threads per dot; fold
//    BN(eval)+sigmoid+gamma/beta into a0/a1/a2 stencil coefficients
//  - 3-tap channel stencil, rolling register window over SPC=16 channels,
//    2 independent loads + 2 NT stores per iteration (latency hiding).
// x reads: NORMAL loads (x is L3-resident after gap pass).
// out writes: NON-TEMPORAL (write-once; must not evict x from L3 mid-pass).
// Reflect edges: c==0 uses x[1]; c==C-1 uses x[C-2].
// 1024 blocks -> 4 blocks/CU (co-resident), 16 waves/CU.
// ---------------------------------------------------------------------------
__global__ __launch_bounds__(256) void stencil_kernel(
        const float* __restrict__ x, const float* __restrict__ gap,
        const float* __restrict__ conv_w,
        const float* __restrict__ bn_w, const float* __restrict__ bn_b,
        const float* __restrict__ bn_mean, const float* __restrict__ bn_var,
        const float* __restrict__ gamma, const float* __restrict__ beta,
        float* __restrict__ out) {
    const int blk   = blockIdx.x;
    const int half  = blk & 1;                     // which 512-f4 chunk of HW4
    const int strip = (blk >> 1) & (NSTRIP - 1);
    const int b     = blk >> 5;
    const int c0    = strip * SPC;
    const int t     = threadIdx.x;

    // ---- issue first stencil loads early; in flight across filter phase
    const f4* px = (const f4*)x;
    const size_t base0 = (size_t)b * Cn * HW4n + (size_t)half * 512 + t;
    const size_t base1 = base0 + 256;
    const int cm = (c0 == 0) ? 1 : c0 - 1;         // reflect at c=0
    f4 xm0 = px[base0 + (size_t)cm * HW4n];
    f4 xm1 = px[base1 + (size_t)cm * HW4n];
    f4 xc0 = px[base0 + (size_t)c0 * HW4n];
    f4 xc1 = px[base1 + (size_t)c0 * HW4n];

    // ---- filter phase: 48 outputs (k=0..2, cc=0..15), 4-way split-K ----
    __shared__ __align__(16) float gap_s[Cn];
    __shared__ float a0s[SPC], a1s[SPC], a2s[SPC];
    gap_s[t] = gap[b * Cn + t];
    __syncthreads();
    if (t < 192) {
        const int ol = t >> 2, p = t & 3;          // ol = k*16+cc
        const int k = ol >> 4, cc = ol & 15;
        const int c = c0 + cc;
        const int o = k * Cn + c;
        const f4* w4 = (const f4*)(conv_w + (size_t)o * Cn) + p * 16;
        const f4* g4 = ((const f4*)gap_s) + p * 16;
        float acc = 0.f;
#pragma unroll
        for (int i = 0; i < 16; ++i) {
            f4 g = g4[i], w = w4[i];
            acc += g.x * w.x + g.y * w.y + g.z * w.z + g.w * w.w;
        }
        acc += __shfl_down(acc, 2, 4);
        acc += __shfl_down(acc, 1, 4);
        if (p == 0) {
            float fv = (acc - bn_mean[o]) * rsqrtf(bn_var[o] + BN_EPS) * bn_w[o] + bn_b[o];
            float sg = 1.0f / (1.0f + expf(-fv));
            float a  = (k == 1) ? (sg * gamma[c] + beta[c]) : (sg * gamma[c]);
            if (k == 0) a0s[cc] = a; else if (k == 1) a1s[cc] = a; else a2s[cc] = a;
        }
    }
    __syncthreads();

    // ---- stencil phase: rolling register window, 2 pixels/thread --------
    f4* pout = (f4*)out;
#pragma unroll 4
    for (int i = 0; i < SPC; ++i) {
        const int c   = c0 + i;
        const int cnn = (c == Cn - 1) ? (Cn - 2) : (c + 1);  // reflect at c=C-1
        f4 xn0 = px[base0 + (size_t)cnn * HW4n];
        f4 xn1 = px[base1 + (size_t)cnn * HW4n];
        const float a0 = a0s[i], a1 = a1s[i], a2 = a2s[i];
        f4 o0, o1;
        o0.x = fmaf(a0, xm0.x, fmaf(a1, xc0.x, a2 * xn0.x));
        o0.y = fmaf(a0, xm0.y, fmaf(a1, xc0.y, a2 * xn0.y));
        o0.z = fmaf(a0, xm0.z, fmaf(a1, xc0.z, a2 * xn0.z));
        o0.w = fmaf(a0, xm0.w, fmaf(a1, xc0.w, a2 * xn0.w));
        o1.x = fmaf(a0, xm1.x, fmaf(a1, xc1.x, a2 * xn1.x));
        o1.y = fmaf(a0, xm1.y, fmaf(a1, xc1.y, a2 * xn1.y));
        o1.z = fmaf(a0, xm1.z, fmaf(a1, xc1.z, a2 * xn1.z));
        o1.w = fmaf(a0, xm1.w, fmaf(a1, xc1.w, a2 * xn1.w));
        __builtin_nontemporal_store(o0, &pout[base0 + (size_t)c * HW4n]);
        __builtin_nontemporal_store(o1, &pout[base1 + (size_t)c * HW4n]);
        xm0 = xc0; xc0 = xn0;
        xm1 = xc1; xc1 = xn1;
    }
}

extern "C" void kernel_launch(void* const* d_in, const int* in_sizes, int n_in,
                              void* d_out, int out_size, void* d_ws, size_t ws_size,
                              hipStream_t stream) {
    const float* x       = (const float*)d_in[0];
    const float* conv_w  = (const float*)d_in[1];
    const float* bn_w    = (const float*)d_in[2];
    const float* bn_b    = (const float*)d_in[3];
    const float* bn_mean = (const float*)d_in[4];
    const float* bn_var  = (const float*)d_in[5];
    const float* gamma   = (const float*)d_in[6];
    const float* beta    = (const float*)d_in[7];
    float* out = (float*)d_out;

    float* gap = (float*)d_ws;            // [B*C] = 32 KiB

    gap_kernel<<<Bn * Cn, 256, 0, stream>>>(x, gap);
    stencil_kernel<<<(Bn * NSTRIP * 2), 256, 0, stream>>>(
        x, gap, conv_w, bn_w, bn_b, bn_mean, bn_var, gamma, beta, out);
}